// Round 1
// baseline (173.331 us; speedup 1.0000x reference)
//
#include <hip/hip_runtime.h>

// ModConv: y[b,o,p] = d[b,o] * sum_{c,tap} weight[o,c,tap] * style[b,c] * x[b,c,p+tap]
// Implemented as: prologue (style, W2, d, bf16 repacks) + bf16 MFMA implicit-GEMM conv.

typedef __attribute__((ext_vector_type(8))) short bfx8;
typedef __attribute__((ext_vector_type(4))) float f32x4;

__device__ __forceinline__ unsigned short f2bf(float f) {
    unsigned int u = __builtin_bit_cast(unsigned int, f);
    u += 0x7FFFu + ((u >> 16) & 1u);          // round-to-nearest-even
    return (unsigned short)(u >> 16);
}

__device__ __forceinline__ void gload_lds16(const void* g, void* l) {
    __builtin_amdgcn_global_load_lds(
        (const __attribute__((address_space(1))) unsigned int*)g,
        (__attribute__((address_space(3))) unsigned int*)l,
        16, 0, 0);
}

// ---------- prologue ----------

// style[b][c] = dot(w[b,:], affine_w[c,:]) + affine_b[c]   (16 x 512)
__global__ void style_kernel(const float* __restrict__ w,
                             const float* __restrict__ affine_w,
                             const float* __restrict__ affine_b,
                             float* __restrict__ style) {
    const int b = blockIdx.x, c = threadIdx.x;     // 512 threads
    __shared__ float wsh[512];
    wsh[c] = w[b * 512 + c];
    __syncthreads();
    const float* row = affine_w + (size_t)c * 512;
    float acc = 0.f;
    #pragma unroll 8
    for (int j = 0; j < 512; ++j) acc += wsh[j] * row[j];
    style[b * 512 + c] = acc + affine_b[c];
}

// W2[o][c] = sum_kk weight[o,c,:,:]^2    (512 x 512)
__global__ void w2_kernel(const float* __restrict__ weight, float* __restrict__ W2) {
    const int idx = blockIdx.x * 256 + threadIdx.x;     // 262144
    const float* p = weight + (size_t)idx * 9;
    float s = 0.f;
    #pragma unroll
    for (int i = 0; i < 9; ++i) { float v = p[i]; s += v * v; }
    W2[idx] = s;
}

// d[b][o] = rsqrt(sum_c style[b,c]^2 * W2[o,c] + eps)
__global__ void d_kernel(const float* __restrict__ style,
                         const float* __restrict__ W2,
                         float* __restrict__ dcoef) {
    const int b = blockIdx.x, o = threadIdx.x;     // 512 threads
    __shared__ float s2[512];
    float sv = style[b * 512 + o];
    s2[o] = sv * sv;
    __syncthreads();
    const float* row = W2 + (size_t)o * 512;
    float acc = 0.f;
    #pragma unroll 8
    for (int c = 0; c < 512; ++c) acc += s2[c] * row[c];
    dcoef[b * 512 + o] = rsqrtf(acc + 1e-8f);
}

// wbf[(t*8+q)][oc][64] bf16, XOR-swizzle baked: within each 64-ch chunk,
// 16B sub-block s of row oc stored at position s ^ (oc&7).
__global__ void wbf_kernel(const float* __restrict__ weight, unsigned short* __restrict__ wbf) {
    const int idx = blockIdx.x * 256 + threadIdx.x;      // 72*512*64 = 2359296
    const int c_local = idx & 63;
    const int oc = (idx >> 6) & 511;
    const int tq = idx >> 15;                 // t*8+q, 0..71
    const int q = tq & 7, t = tq >> 3;
    const int c = q * 64 + c_local;
    const int ky = t / 3, kx = t - ky * 3;
    const float v = weight[((size_t)oc * 512 + c) * 9 + ky * 3 + kx];
    const int s = c_local >> 3, j = c_local & 7;
    const int pos = ((s ^ (oc & 7)) << 3) | j;
    wbf[((size_t)tq * 512 + oc) * 64 + pos] = f2bf(v);
}

// xs_pad[b][34][34][512] bf16 (NHWC, zero border via prior memset):
// interior [r=h+1][cc=w+1][c] = x[b,c,h,w] * style[b,c]
__global__ void xspad_kernel(const float* __restrict__ x,
                             const float* __restrict__ style,
                             unsigned short* __restrict__ xs) {
    __shared__ float tile[128][33];
    const int b = blockIdx.z, h = blockIdx.y, c0 = blockIdx.x * 128;
    const int tid = threadIdx.x;               // 256
    #pragma unroll
    for (int i = 0; i < 16; ++i) {             // read coalesced along w (NCHW)
        const int ch = i * 8 + (tid >> 5), w_ = tid & 31;
        tile[ch][w_] = x[(((size_t)b * 512 + c0 + ch) * 32 + h) * 32 + w_];
    }
    __syncthreads();
    const float sv = style[b * 512 + c0 + (tid & 127)];
    #pragma unroll
    for (int i = 0; i < 16; ++i) {             // write coalesced along c (NHWC)
        const int w_ = i * 2 + (tid >> 7), ch = tid & 127;
        xs[(((size_t)b * 34 + (h + 1)) * 34 + (w_ + 1)) * 512 + c0 + ch] =
            f2bf(tile[ch][w_] * sv);
    }
}

// ---------- main conv: implicit GEMM, 128x128 tile, BK=64, 72 K-steps ----------
__global__ __launch_bounds__(256, 2) void conv_kernel(
    const unsigned short* __restrict__ wbf,
    const unsigned short* __restrict__ xs,
    const float* __restrict__ dcoef,
    float* __restrict__ out) {
    __shared__ char lds[32768];
    char* ldsA = lds;                 // 128 oc  x 64 k x bf16 (swizzled)
    char* ldsB = lds + 16384;         // 128 px  x 64 k x bf16 (swizzled)

    const int id = blockIdx.x;        // 512 = 16 b * 4 octile * 8 pxtile
    const int b = id >> 5;
    const int rem = id & 31;
    const int oc0 = (rem >> 3) << 7;
    const int n0  = (rem & 7) << 7;

    const int tid = threadIdx.x;
    const int lane = tid & 63;
    const int wv = tid >> 6;
    const int wr = wv >> 1, wc = wv & 1;
    const int l7 = lane & 7, l15 = lane & 15;

    f32x4 acc[4][4];
    #pragma unroll
    for (int i = 0; i < 4; ++i)
        #pragma unroll
        for (int j = 0; j < 4; ++j) acc[i][j] = (f32x4){0.f, 0.f, 0.f, 0.f};

    // staging constants: wave wv owns LDS segments wv*4..wv*4+3 (1KB each)
    int rowl[4];        // row (oc_local == px_local) covered by this lane, per segment
    size_t bbase0[4];   // xs base for tap (0,0): b + pixel + swizzled sub-block
    const size_t xsb = (size_t)b * (34 * 34 * 512);
    #pragma unroll
    for (int i = 0; i < 4; ++i) {
        const int seg = wv * 4 + i;
        const int p = seg * 8 + (lane >> 3);
        rowl[i] = p;
        const int n = n0 + p;
        const int hh = n >> 5, ww = n & 31;
        const int sub = l7 ^ (p & 7);           // pre-swizzled global source (T2 via m173)
        bbase0[i] = xsb + ((size_t)hh * 34 + ww) * 512 + sub * 8;
    }

    for (int s = 0; s < 72; ++s) {
        const int t = s >> 3, q = s & 7;
        const int ky = t / 3, kx = t - ky * 3;
        const int shift = (ky * 34 + kx) * 512 + q * 64;
        #pragma unroll
        for (int i = 0; i < 4; ++i) {           // stage A (weights, swizzle baked in wbf)
            const int seg = wv * 4 + i;
            const unsigned short* src = wbf + ((size_t)(s * 512 + oc0 + rowl[i])) * 64 + l7 * 8;
            gload_lds16(src, ldsA + seg * 1024);
        }
        #pragma unroll
        for (int i = 0; i < 4; ++i) {           // stage B (shifted NHWC input)
            const int seg = wv * 4 + i;
            gload_lds16(xs + bbase0[i] + shift, ldsB + seg * 1024);
        }
        __syncthreads();
        #pragma unroll
        for (int ks = 0; ks < 2; ++ks) {
            const int kb = ks * 4 + (lane >> 4);
            const int swz = (kb ^ l7) << 4;
            bfx8 af[4], bx[4];
            #pragma unroll
            for (int mi = 0; mi < 4; ++mi)
                af[mi] = *(const bfx8*)(ldsA + (wr * 64 + l15) * 128 + mi * 2048 + swz);
            #pragma unroll
            for (int ni = 0; ni < 4; ++ni)
                bx[ni] = *(const bfx8*)(ldsB + (wc * 64 + l15) * 128 + ni * 2048 + swz);
            #pragma unroll
            for (int mi = 0; mi < 4; ++mi)
                #pragma unroll
                for (int ni = 0; ni < 4; ++ni)
                    acc[mi][ni] = __builtin_amdgcn_mfma_f32_16x16x32_bf16(
                        af[mi], bx[ni], acc[mi][ni], 0, 0, 0);
        }
        __syncthreads();
    }

    // epilogue: scale by demod d[b][oc], write fp32 NCHW
    const int r4 = (lane >> 4) * 4;
    #pragma unroll
    for (int mi = 0; mi < 4; ++mi) {
        #pragma unroll
        for (int rr = 0; rr < 4; ++rr) {
            const int ocr = oc0 + wr * 64 + mi * 16 + r4 + rr;
            const float dv = dcoef[b * 512 + ocr];
            float* orow = out + ((size_t)b * 512 + ocr) * 1024 + n0 + wc * 64 + l15;
            #pragma unroll
            for (int ni = 0; ni < 4; ++ni)
                orow[ni * 16] = acc[mi][ni][rr] * dv;
        }
    }
}

// ---------- launch ----------
extern "C" void kernel_launch(void* const* d_in, const int* in_sizes, int n_in,
                              void* d_out, int out_size, void* d_ws, size_t ws_size,
                              hipStream_t stream) {
    const float* x        = (const float*)d_in[0];   // (16,512,32,32)
    const float* w        = (const float*)d_in[1];   // (16,512)
    const float* weight   = (const float*)d_in[2];   // (512,512,3,3)
    const float* affine_w = (const float*)d_in[3];   // (512,512)
    const float* affine_b = (const float*)d_in[4];   // (512,)
    float* out = (float*)d_out;

    char* ws = (char*)d_ws;
    float*          style = (float*)(ws + 0);                 // 32 KB
    float*          W2    = (float*)(ws + 0x8000);            // 1 MB
    float*          dcoef = (float*)(ws + 0x108000);          // 32 KB
    unsigned short* wbf   = (unsigned short*)(ws + 0x110000); // 4.5 MB
    unsigned short* xs    = (unsigned short*)(ws + 0x590000); // 18.1 MB

    hipMemsetAsync(xs, 0, (size_t)16 * 34 * 34 * 512 * 2, stream);  // zero pad border
    style_kernel<<<16, 512, 0, stream>>>(w, affine_w, affine_b, style);
    w2_kernel<<<1024, 256, 0, stream>>>(weight, W2);
    d_kernel<<<16, 512, 0, stream>>>(style, W2, dcoef);
    wbf_kernel<<<9216, 256, 0, stream>>>(weight, wbf);
    xspad_kernel<<<dim3(4, 32, 16), 256, 0, stream>>>(x, style, xs);
    conv_kernel<<<512, 256, 0, stream>>>(wbf, xs, dcoef, out);
}

// Round 2
// 104.482 us; speedup vs baseline: 1.6590x; 1.6590x over previous
//
#include <hip/hip_runtime.h>

// ModConv: y[b,o,p] = d[b,o] * sum_{c,tap} weight[o,c,tap] * style[b,c] * x[b,c,p+tap]
// Prologue (style, W2+wbf fused, d, border-zero, xspad) + bf16 MFMA implicit-GEMM conv.

typedef __attribute__((ext_vector_type(8))) short bfx8;
typedef __attribute__((ext_vector_type(4))) float f32x4;
typedef __attribute__((ext_vector_type(4))) unsigned short us4;
typedef __attribute__((ext_vector_type(8))) unsigned short us8;

__device__ __forceinline__ unsigned short f2bf(float f) {
    unsigned int u = __builtin_bit_cast(unsigned int, f);
    u += 0x7FFFu + ((u >> 16) & 1u);          // round-to-nearest-even
    return (unsigned short)(u >> 16);
}

__device__ __forceinline__ void gload_lds16(const void* g, void* l) {
    __builtin_amdgcn_global_load_lds(
        (const __attribute__((address_space(1))) unsigned int*)g,
        (__attribute__((address_space(3))) unsigned int*)l,
        16, 0, 0);
}

__device__ __forceinline__ float wave_sum(float v) {
    #pragma unroll
    for (int m = 1; m < 64; m <<= 1) v += __shfl_xor(v, m, 64);
    return v;
}

// ---------- prologue ----------

// style[b][c] = dot(w[b,:], affine_w[c,:]) + affine_b[c]; wave-per-output (8192 waves)
__global__ void style_kernel(const float* __restrict__ w,
                             const float* __restrict__ affine_w,
                             const float* __restrict__ affine_b,
                             float* __restrict__ style) {
    const int out = blockIdx.x * 4 + (threadIdx.x >> 6);
    const int lane = threadIdx.x & 63;
    const int b = out >> 9, c = out & 511;
    const float4 a0 = *(const float4*)(affine_w + (size_t)c * 512 + lane * 8);
    const float4 a1 = *(const float4*)(affine_w + (size_t)c * 512 + lane * 8 + 4);
    const float4 w0 = *(const float4*)(w + (size_t)b * 512 + lane * 8);
    const float4 w1 = *(const float4*)(w + (size_t)b * 512 + lane * 8 + 4);
    float acc = a0.x * w0.x + a0.y * w0.y + a0.z * w0.z + a0.w * w0.w
              + a1.x * w1.x + a1.y * w1.y + a1.z * w1.z + a1.w * w1.w;
    acc = wave_sum(acc);
    if (lane == 0) style[out] = acc + affine_b[c];
}

// Fused: W2[o][c] = sum_kk weight[o,c,:,:]^2  AND  wbf bf16 repack (swizzle baked).
// wbf[(t*8+q)][oc][64]: 16B sub-block s of row oc stored at position s ^ (oc&7).
__global__ void w2wbf_kernel(const float* __restrict__ weight,
                             float* __restrict__ W2,
                             unsigned short* __restrict__ wbf) {
    const int idx = blockIdx.x * 256 + threadIdx.x;   // 262144 = oc*512 + c
    const int oc = idx >> 9, c = idx & 511;
    const int q = c >> 6, c_local = c & 63;
    const int s = c_local >> 3, j = c_local & 7;
    const int pos = ((s ^ (oc & 7)) << 3) | j;
    const float* p = weight + (size_t)idx * 9;
    float ss = 0.f;
    #pragma unroll
    for (int t = 0; t < 9; ++t) {
        const float v = p[t];
        ss += v * v;
        wbf[((size_t)(t * 8 + q) * 512 + oc) * 64 + pos] = f2bf(v);
    }
    W2[idx] = ss;
}

// d[b][o] = rsqrt(sum_c style[b,c]^2 * W2[o,c] + eps); wave-per-output
__global__ void d_kernel(const float* __restrict__ style,
                         const float* __restrict__ W2,
                         float* __restrict__ dcoef) {
    const int out = blockIdx.x * 4 + (threadIdx.x >> 6);
    const int lane = threadIdx.x & 63;
    const int b = out >> 9, o = out & 511;
    const float4 s0 = *(const float4*)(style + (size_t)b * 512 + lane * 8);
    const float4 s1 = *(const float4*)(style + (size_t)b * 512 + lane * 8 + 4);
    const float4 v0 = *(const float4*)(W2 + (size_t)o * 512 + lane * 8);
    const float4 v1 = *(const float4*)(W2 + (size_t)o * 512 + lane * 8 + 4);
    float acc = s0.x * s0.x * v0.x + s0.y * s0.y * v0.y
              + s0.z * s0.z * v0.z + s0.w * s0.w * v0.w
              + s1.x * s1.x * v1.x + s1.y * s1.y * v1.y
              + s1.z * s1.z * v1.z + s1.w * s1.w * v1.w;
    acc = wave_sum(acc);
    if (lane == 0) dcoef[out] = rsqrtf(acc + 1e-8f);
}

// zero only the 132-cell pad border of xs[b][34][34][512] (2.2 MB, not 18 MB)
__global__ void border_kernel(unsigned short* __restrict__ xs) {
    const int idx = blockIdx.x * 256 + threadIdx.x;   // 16*132*128 = 270336
    const int b = idx / (132 * 128);
    const int r_ = idx - b * (132 * 128);
    const int cell = r_ >> 7, t = r_ & 127;
    int rr, cc;
    if (cell < 34)      { rr = 0;  cc = cell; }
    else if (cell < 68) { rr = 33; cc = cell - 34; }
    else { const int jj = cell - 68; rr = 1 + (jj >> 1); cc = (jj & 1) ? 33 : 0; }
    us4 z = (us4){0, 0, 0, 0};
    *(us4*)(xs + (((size_t)b * 34 + rr) * 34 + cc) * 512 + t * 4) = z;
}

// xs_pad[b][34][34][512] bf16 (NHWC): interior [h+1][w+1][c] = x[b,c,h,w]*style[b,c]
// float4 reads, LDS transpose (bf16), ushort8 (16B) stores.
__global__ void xspad_kernel(const float* __restrict__ x,
                             const float* __restrict__ style,
                             unsigned short* __restrict__ xs) {
    __shared__ __align__(16) unsigned short tile[128][36];
    const int b = blockIdx.z, h = blockIdx.y, c0 = blockIdx.x * 128;
    const int tid = threadIdx.x;               // 256
    #pragma unroll
    for (int it = 0; it < 4; ++it) {           // 1024 float4 reads, coalesced
        const int e = it * 256 + tid;
        const int ch = e >> 3, w4 = e & 7;
        const float4 v = *(const float4*)(x + (((size_t)b * 512 + c0 + ch) * 32 + h) * 32 + w4 * 4);
        const float sv = style[b * 512 + c0 + ch];
        us4 o;
        o.x = f2bf(v.x * sv); o.y = f2bf(v.y * sv);
        o.z = f2bf(v.z * sv); o.w = f2bf(v.w * sv);
        *(us4*)&tile[ch][w4 * 4] = o;
    }
    __syncthreads();
    #pragma unroll
    for (int it = 0; it < 2; ++it) {           // 512 ushort8 stores, coalesced
        const int e = it * 256 + tid;
        const int cq = e & 15, w_ = e >> 4;
        us8 o;
        #pragma unroll
        for (int i = 0; i < 8; ++i) o[i] = tile[cq * 8 + i][w_];
        *(us8*)(xs + (((size_t)b * 34 + (h + 1)) * 34 + (w_ + 1)) * 512 + c0 + cq * 8) = o;
    }
}

// ---------- main conv: implicit GEMM, 128x128 tile, BK=64, 72 K-steps ----------
__global__ __launch_bounds__(256, 2) void conv_kernel(
    const unsigned short* __restrict__ wbf,
    const unsigned short* __restrict__ xs,
    const float* __restrict__ dcoef,
    float* __restrict__ out) {
    __shared__ char lds[32768];
    char* ldsA = lds;                 // 128 oc  x 64 k x bf16 (swizzled)
    char* ldsB = lds + 16384;         // 128 px  x 64 k x bf16 (swizzled)

    const int id = blockIdx.x;        // 512 = 16 b * 4 octile * 8 pxtile
    const int b = id >> 5;
    const int rem = id & 31;
    const int oc0 = (rem >> 3) << 7;
    const int n0  = (rem & 7) << 7;

    const int tid = threadIdx.x;
    const int lane = tid & 63;
    const int wv = tid >> 6;
    const int wr = wv >> 1, wc = wv & 1;
    const int l7 = lane & 7, l15 = lane & 15;

    f32x4 acc[4][4];
    #pragma unroll
    for (int i = 0; i < 4; ++i)
        #pragma unroll
        for (int j = 0; j < 4; ++j) acc[i][j] = (f32x4){0.f, 0.f, 0.f, 0.f};

    int rowl[4];
    size_t bbase0[4];
    const size_t xsb = (size_t)b * (34 * 34 * 512);
    #pragma unroll
    for (int i = 0; i < 4; ++i) {
        const int seg = wv * 4 + i;
        const int p = seg * 8 + (lane >> 3);
        rowl[i] = p;
        const int n = n0 + p;
        const int hh = n >> 5, ww = n & 31;
        const int sub = l7 ^ (p & 7);           // pre-swizzled global source (T2 via m173)
        bbase0[i] = xsb + ((size_t)hh * 34 + ww) * 512 + sub * 8;
    }

    for (int s = 0; s < 72; ++s) {
        const int t = s >> 3, q = s & 7;
        const int ky = t / 3, kx = t - ky * 3;
        const int shift = (ky * 34 + kx) * 512 + q * 64;
        #pragma unroll
        for (int i = 0; i < 4; ++i) {           // stage A (weights, swizzle baked in wbf)
            const int seg = wv * 4 + i;
            const unsigned short* src = wbf + ((size_t)(s * 512 + oc0 + rowl[i])) * 64 + l7 * 8;
            gload_lds16(src, ldsA + seg * 1024);
        }
        #pragma unroll
        for (int i = 0; i < 4; ++i) {           // stage B (shifted NHWC input)
            const int seg = wv * 4 + i;
            gload_lds16(xs + bbase0[i] + shift, ldsB + seg * 1024);
        }
        __syncthreads();
        #pragma unroll
        for (int ks = 0; ks < 2; ++ks) {
            const int kb = ks * 4 + (lane >> 4);
            const int swz = (kb ^ l7) << 4;
            bfx8 af[4], bx[4];
            #pragma unroll
            for (int mi = 0; mi < 4; ++mi)
                af[mi] = *(const bfx8*)(ldsA + (wr * 64 + l15) * 128 + mi * 2048 + swz);
            #pragma unroll
            for (int ni = 0; ni < 4; ++ni)
                bx[ni] = *(const bfx8*)(ldsB + (wc * 64 + l15) * 128 + ni * 2048 + swz);
            #pragma unroll
            for (int mi = 0; mi < 4; ++mi)
                #pragma unroll
                for (int ni = 0; ni < 4; ++ni)
                    acc[mi][ni] = __builtin_amdgcn_mfma_f32_16x16x32_bf16(
                        af[mi], bx[ni], acc[mi][ni], 0, 0, 0);
        }
        __syncthreads();
    }

    const int r4 = (lane >> 4) * 4;
    #pragma unroll
    for (int mi = 0; mi < 4; ++mi) {
        #pragma unroll
        for (int rr = 0; rr < 4; ++rr) {
            const int ocr = oc0 + wr * 64 + mi * 16 + r4 + rr;
            const float dv = dcoef[b * 512 + ocr];
            float* orow = out + ((size_t)b * 512 + ocr) * 1024 + n0 + wc * 64 + l15;
            #pragma unroll
            for (int ni = 0; ni < 4; ++ni)
                orow[ni * 16] = acc[mi][ni][rr] * dv;
        }
    }
}

// ---------- launch ----------
extern "C" void kernel_launch(void* const* d_in, const int* in_sizes, int n_in,
                              void* d_out, int out_size, void* d_ws, size_t ws_size,
                              hipStream_t stream) {
    const float* x        = (const float*)d_in[0];   // (16,512,32,32)
    const float* w        = (const float*)d_in[1];   // (16,512)
    const float* weight   = (const float*)d_in[2];   // (512,512,3,3)
    const float* affine_w = (const float*)d_in[3];   // (512,512)
    const float* affine_b = (const float*)d_in[4];   // (512,)
    float* out = (float*)d_out;

    char* ws = (char*)d_ws;
    float*          style = (float*)(ws + 0);                 // 32 KB
    float*          W2    = (float*)(ws + 0x8000);            // 1 MB
    float*          dcoef = (float*)(ws + 0x108000);          // 32 KB
    unsigned short* wbf   = (unsigned short*)(ws + 0x110000); // 4.5 MB
    unsigned short* xs    = (unsigned short*)(ws + 0x590000); // 18.1 MB

    style_kernel<<<2048, 256, 0, stream>>>(w, affine_w, affine_b, style);
    w2wbf_kernel<<<1024, 256, 0, stream>>>(weight, W2, wbf);
    d_kernel<<<2048, 256, 0, stream>>>(style, W2, dcoef);
    border_kernel<<<1056, 256, 0, stream>>>(xs);
    xspad_kernel<<<dim3(4, 32, 16), 256, 0, stream>>>(x, style, xs);
    conv_kernel<<<512, 256, 0, stream>>>(wbf, xs, dcoef, out);
}